// Round 12
// baseline (413.696 us; speedup 1.0000x reference)
//
#include <hip/hip_runtime.h>
#include <hip/hip_bf16.h>

typedef __bf16 bf16_t;
typedef __bf16 bf16x8 __attribute__((ext_vector_type(8)));
typedef __bf16 bf16x4 __attribute__((ext_vector_type(4)));
typedef float f32x4 __attribute__((ext_vector_type(4)));

#define B_ 256
#define S_ 128
#define E_ 256
#define H_ 4
#define HD_ 64
#define F_ 1024
#define TPOS_ 100
#define TNEG_ 500
#define TT_ 600
#define ROWS_ (B_ * S_)   // 32768
#define V_ 50000
#define VPAD_ 50176       // 1024*49 coverage for scan

// ---------------- all-weights fp32 -> bf16 convert (one launch) ----------------
__global__ __launch_bounds__(256) void cvtall_kernel(
        const float* __restrict__ sq, const float* __restrict__ sa,
        const float* __restrict__ s1, const float* __restrict__ s2,
        bf16_t* __restrict__ dq, bf16_t* __restrict__ da,
        bf16_t* __restrict__ d1, bf16_t* __restrict__ d2) {
    int i = blockIdx.x * 256 + threadIdx.x;
    if (i < 393216) { dq[i] = (bf16_t)sq[i]; }
    else if (i < 524288) { int j = i - 393216; da[j] = (bf16_t)sa[j]; }
    else if (i < 1048576) { int j = i - 524288; d1[j] = (bf16_t)s1[j]; }
    else { int j = i - 1048576; d2[j] = (bf16_t)s2[j]; }
}

// ---------------- embedding gather -> xb bf16 ----------------
__global__ __launch_bounds__(256) void embed_kernel(const int* __restrict__ attr,
        const float* __restrict__ emb, bf16_t* __restrict__ xb) {
    int row = blockIdx.x * 4 + (threadIdx.x >> 6);
    int lane = threadIdx.x & 63;
    int idx = attr[row];
    float4 v = reinterpret_cast<const float4*>(emb + (size_t)idx * E_)[lane];
    bf16x4 o; o[0] = (bf16_t)v.x; o[1] = (bf16_t)v.y; o[2] = (bf16_t)v.z; o[3] = (bf16_t)v.w;
    *reinterpret_cast<bf16x4*>(xb + (size_t)row * E_ + lane * 4) = o;
}

// ---------------- GEMM 8-wave: C[M,N] = A[M,K] @ W[N,K]^T + bias -> bf16 ----------------
template<bool RELU>
__global__ __launch_bounds__(512) void gemm8_kernel(
        const bf16_t* __restrict__ A, const bf16_t* __restrict__ W,
        const float* __restrict__ bias, bf16_t* __restrict__ outB, int M, int N, int K) {
    __shared__ bf16_t lA[2][128 * 32];
    __shared__ bf16_t lB[2][256 * 32];
    int tid = threadIdx.x;
    int wave = tid >> 6, lane = tid & 63;
    int wm = wave >> 2, wn = wave & 3;
    int mBase = blockIdx.y * 128;
    int nBase = blockIdx.x * 256;
    int r16 = lane & 15, kg = lane >> 4;

    const bf16_t* gA = A + (size_t)(mBase + (tid >> 2)) * K + (tid & 3) * 8;
    const bf16_t* gB = W + (size_t)(nBase + (tid >> 2)) * K + (tid & 3) * 8;

    f32x4 acc[4][4] = {};

    #define STG(buf, k0) { \
        __builtin_amdgcn_global_load_lds( \
            (const __attribute__((address_space(1))) void*)(gA + (k0)), \
            (__attribute__((address_space(3))) void*)(&lA[buf][wave * 512]), 16, 0, 0); \
        _Pragma("unroll") \
        for (int iss = 0; iss < 2; iss++) { \
            __builtin_amdgcn_global_load_lds( \
                (const __attribute__((address_space(1))) void*)(gB + (size_t)iss * 128 * K + (k0)), \
                (__attribute__((address_space(3))) void*)(&lB[buf][iss * 4096 + wave * 512]), 16, 0, 0); \
        } }

    STG(0, 0);
    int cur = 0;
    for (int k0 = 0; k0 < K; k0 += 32) {
        __syncthreads();
        if (k0 + 32 < K) STG(cur ^ 1, k0 + 32);
        bf16x8 a[4], b[4];
        #pragma unroll
        for (int i = 0; i < 4; i++) {
            a[i] = *reinterpret_cast<const bf16x8*>(&lA[cur][(wm * 64 + i * 16 + r16) * 32 + kg * 8]);
            b[i] = *reinterpret_cast<const bf16x8*>(&lB[cur][(wn * 64 + i * 16 + r16) * 32 + kg * 8]);
        }
        #pragma unroll
        for (int mi = 0; mi < 4; mi++)
            #pragma unroll
            for (int ni = 0; ni < 4; ni++)
                acc[mi][ni] = __builtin_amdgcn_mfma_f32_16x16x32_bf16(a[mi], b[ni], acc[mi][ni], 0, 0, 0);
        cur ^= 1;
    }
    #undef STG

    #pragma unroll
    for (int mi = 0; mi < 4; mi++) {
        #pragma unroll
        for (int ni = 0; ni < 4; ni++) {
            int col = nBase + wn * 64 + ni * 16 + r16;
            float bv = bias[col];
            #pragma unroll
            for (int j = 0; j < 4; j++) {
                int row = mBase + wm * 64 + mi * 16 + kg * 4 + j;
                float v = acc[mi][ni][j] + bv;
                if (RELU) v = v > 0.f ? v : 0.f;
                outB[(size_t)row * N + col] = (bf16_t)v;
            }
        }
    }
}

// ---------------- fused GEMM + bias + residual + LayerNorm, 8-wave (N=256) ----------------
__global__ __launch_bounds__(512) void gemm_ln8_kernel(
        const bf16_t* __restrict__ A, const bf16_t* __restrict__ W,
        const float* __restrict__ bias, const float* __restrict__ sc,
        const float* __restrict__ bi, bf16_t* __restrict__ xb, int M, int K) {
    __shared__ bf16_t lA[2][128 * 32];
    __shared__ bf16_t lB[2][256 * 32];
    __shared__ float psum[128][4][2];
    int tid = threadIdx.x;
    int wave = tid >> 6, lane = tid & 63;
    int wm = wave >> 2, wn = wave & 3;
    int mBase = blockIdx.x * 128;
    int r16 = lane & 15, kg = lane >> 4;

    const bf16_t* gA = A + (size_t)(mBase + (tid >> 2)) * K + (tid & 3) * 8;
    const bf16_t* gB = W + (size_t)((tid >> 2)) * K + (tid & 3) * 8;

    f32x4 acc[4][4] = {};

    #define STG2(buf, k0) { \
        __builtin_amdgcn_global_load_lds( \
            (const __attribute__((address_space(1))) void*)(gA + (k0)), \
            (__attribute__((address_space(3))) void*)(&lA[buf][wave * 512]), 16, 0, 0); \
        _Pragma("unroll") \
        for (int iss = 0; iss < 2; iss++) { \
            __builtin_amdgcn_global_load_lds( \
                (const __attribute__((address_space(1))) void*)(gB + (size_t)iss * 128 * K + (k0)), \
                (__attribute__((address_space(3))) void*)(&lB[buf][iss * 4096 + wave * 512]), 16, 0, 0); \
        } }

    STG2(0, 0);
    int cur = 0;
    for (int k0 = 0; k0 < K; k0 += 32) {
        __syncthreads();
        if (k0 + 32 < K) STG2(cur ^ 1, k0 + 32);
        bf16x8 a[4], b[4];
        #pragma unroll
        for (int i = 0; i < 4; i++) {
            a[i] = *reinterpret_cast<const bf16x8*>(&lA[cur][(wm * 64 + i * 16 + r16) * 32 + kg * 8]);
            b[i] = *reinterpret_cast<const bf16x8*>(&lB[cur][(wn * 64 + i * 16 + r16) * 32 + kg * 8]);
        }
        #pragma unroll
        for (int mi = 0; mi < 4; mi++)
            #pragma unroll
            for (int ni = 0; ni < 4; ni++)
                acc[mi][ni] = __builtin_amdgcn_mfma_f32_16x16x32_bf16(a[mi], b[ni], acc[mi][ni], 0, 0, 0);
        cur ^= 1;
    }
    #undef STG2

    float bv[4];
    #pragma unroll
    for (int ni = 0; ni < 4; ni++) bv[ni] = bias[wn * 64 + ni * 16 + r16];
    #pragma unroll
    for (int mi = 0; mi < 4; mi++) {
        #pragma unroll
        for (int j = 0; j < 4; j++) {
            int rl = wm * 64 + mi * 16 + kg * 4 + j;
            const bf16_t* rrow = xb + (size_t)(mBase + rl) * 256;
            float s = 0.f, q = 0.f;
            #pragma unroll
            for (int ni = 0; ni < 4; ni++) {
                int col = wn * 64 + ni * 16 + r16;
                float v = acc[mi][ni][j] + bv[ni] + (float)rrow[col];
                acc[mi][ni][j] = v;
                s += v; q += v * v;
            }
            #pragma unroll
            for (int m = 1; m < 16; m <<= 1) { s += __shfl_xor(s, m); q += __shfl_xor(q, m); }
            if (r16 == 0) { psum[rl][wn][0] = s; psum[rl][wn][1] = q; }
        }
    }
    __syncthreads();
    #pragma unroll
    for (int mi = 0; mi < 4; mi++) {
        #pragma unroll
        for (int j = 0; j < 4; j++) {
            int rl = wm * 64 + mi * 16 + kg * 4 + j;
            float s = psum[rl][0][0] + psum[rl][1][0] + psum[rl][2][0] + psum[rl][3][0];
            float qq = psum[rl][0][1] + psum[rl][1][1] + psum[rl][2][1] + psum[rl][3][1];
            float mean = s * (1.0f / 256.0f);
            float var = qq * (1.0f / 256.0f) - mean * mean;
            float inv = rsqrtf(var + 1e-5f);
            bf16_t* orow = xb + (size_t)(mBase + rl) * 256;
            #pragma unroll
            for (int ni = 0; ni < 4; ni++) {
                int col = wn * 64 + ni * 16 + r16;
                float o = (acc[mi][ni][j] - mean) * inv * sc[col] + bi[col];
                orow[col] = (bf16_t)o;
            }
        }
    }
}

// ---------------- fused attention per (b,h); V transposed in-kernel via LDS ----------------
__global__ __launch_bounds__(256) void attn_kernel(const bf16_t* __restrict__ qkv,
        const int* __restrict__ lens, bf16_t* __restrict__ out) {
    __shared__ bf16_t p[S_][S_ + 8];
    __shared__ bf16_t vl[HD_][S_ + 8];
    int bh = blockIdx.x; int b = bh >> 2, h = bh & 3;
    int wave = threadIdx.x >> 6, lane = threadIdx.x & 63;
    int r16 = lane & 15, kg = lane >> 4;
    int q0 = wave * 32;
    int len = lens[b];
    const bf16_t* qbase = qkv + (size_t)b * S_ * 768;

    {
        int sl = (wave & 1) * 64 + lane;
        const bf16_t* vsrc = qbase + (size_t)sl * 768 + 512 + h * HD_;
        #pragma unroll
        for (int pass = 0; pass < 4; pass++) {
            int d0 = (pass * 2 + (wave >> 1)) * 8;
            bf16x8 v = *reinterpret_cast<const bf16x8*>(vsrc + d0);
            #pragma unroll
            for (int j = 0; j < 8; j++) vl[d0 + j][sl] = v[j];
        }
    }

    f32x4 acc[2][8] = {};
    #pragma unroll
    for (int ks = 0; ks < 2; ks++) {
        int kOff = h * HD_ + ks * 32 + kg * 8;
        bf16x8 a[2], bb[8];
        #pragma unroll
        for (int mi = 0; mi < 2; mi++)
            a[mi] = *reinterpret_cast<const bf16x8*>(qbase + (size_t)(q0 + mi * 16 + r16) * 768 + kOff);
        #pragma unroll
        for (int ni = 0; ni < 8; ni++)
            bb[ni] = *reinterpret_cast<const bf16x8*>(qbase + (size_t)(ni * 16 + r16) * 768 + 256 + kOff);
        #pragma unroll
        for (int mi = 0; mi < 2; mi++)
            #pragma unroll
            for (int ni = 0; ni < 8; ni++)
                acc[mi][ni] = __builtin_amdgcn_mfma_f32_16x16x32_bf16(a[mi], bb[ni], acc[mi][ni], 0, 0, 0);
    }
    #pragma unroll
    for (int mi = 0; mi < 2; mi++) {
        #pragma unroll
        for (int j = 0; j < 4; j++) {
            float vals[8]; float mx = -1e30f;
            #pragma unroll
            for (int ni = 0; ni < 8; ni++) {
                int kp = ni * 16 + r16;
                float v = acc[mi][ni][j] * 0.125f;
                vals[ni] = (kp < len) ? v : -1e30f;
                mx = fmaxf(mx, vals[ni]);
            }
            #pragma unroll
            for (int m = 1; m < 16; m <<= 1) mx = fmaxf(mx, __shfl_xor(mx, m));
            float sum = 0.f;
            #pragma unroll
            for (int ni = 0; ni < 8; ni++) {
                vals[ni] = (vals[ni] > -1e29f) ? __expf(vals[ni] - mx) : 0.f;
                sum += vals[ni];
            }
            #pragma unroll
            for (int m = 1; m < 16; m <<= 1) sum += __shfl_xor(sum, m);
            float inv = 1.0f / sum;
            int row = q0 + mi * 16 + kg * 4 + j;
            #pragma unroll
            for (int ni = 0; ni < 8; ni++)
                p[row][ni * 16 + r16] = (bf16_t)(vals[ni] * inv);
        }
    }
    __syncthreads();
    f32x4 acc2[2][4] = {};
    #pragma unroll
    for (int ks = 0; ks < 4; ks++) {
        int k = ks * 32 + kg * 8;
        bf16x8 a[2], bb[4];
        #pragma unroll
        for (int mi = 0; mi < 2; mi++)
            a[mi] = *reinterpret_cast<const bf16x8*>(&p[q0 + mi * 16 + r16][k]);
        #pragma unroll
        for (int ni = 0; ni < 4; ni++)
            bb[ni] = *reinterpret_cast<const bf16x8*>(&vl[ni * 16 + r16][k]);
        #pragma unroll
        for (int mi = 0; mi < 2; mi++)
            #pragma unroll
            for (int ni = 0; ni < 4; ni++)
                acc2[mi][ni] = __builtin_amdgcn_mfma_f32_16x16x32_bf16(a[mi], bb[ni], acc2[mi][ni], 0, 0, 0);
    }
    #pragma unroll
    for (int mi = 0; mi < 2; mi++)
        #pragma unroll
        for (int ni = 0; ni < 4; ni++)
            #pragma unroll
            for (int j = 0; j < 4; j++) {
                int q = q0 + mi * 16 + kg * 4 + j;
                int d = ni * 16 + r16;
                out[((size_t)b * S_ + q) * E_ + h * HD_ + d] = (bf16_t)acc2[mi][ni][j];
            }
}

// ---------------- per-sample user weight ----------------
__global__ void wuser_kernel(const float* __restrict__ feat, const float* __restrict__ W,
                             const float* __restrict__ bb, float* __restrict__ wu) {
    int b = threadIdx.x;
    if (b < B_) {
        float z = bb[0];
        #pragma unroll
        for (int i = 0; i < 13; i++) z += feat[b * 13 + i] * W[i];
        wu[b] = 1.f / (1.f + __expf(-z));
    }
}

// ---------------- pooling + concat -> outvec[B,768] fp32 ----------------
__global__ __launch_bounds__(256) void pool_kernel(
        const bf16_t* __restrict__ xb, const float* __restrict__ attr_tf,
        const int* __restrict__ lens, const int* __restrict__ lens_user,
        const float* __restrict__ wu, const int* __restrict__ uid, const int* __restrict__ iid,
        const float* __restrict__ user_emb, const float* __restrict__ item_emb,
        float* __restrict__ outvec) {
    int b = blockIdx.x, t = threadIdx.x;
    __shared__ float wrow[S_];
    if (t < S_) {
        float w = (t < lens[b]) ? attr_tf[b * S_ + t] : 0.f;
        float side = (t < lens_user[b]) ? wu[b] : (1.f - wu[b]);
        wrow[t] = w * side;
    }
    __syncthreads();
    float acc = 0.f;
    const bf16_t* xr = xb + (size_t)b * S_ * E_ + t;
    #pragma unroll 4
    for (int s = 0; s < S_; s++) acc += wrow[s] * (float)xr[(size_t)s * E_];
    outvec[b * 768 + 256 + t] = acc;
    outvec[b * 768 + t] = user_emb[(size_t)uid[b] * E_ + t];
    outvec[b * 768 + 512 + t] = item_emb[(size_t)iid[b] * E_ + t];
}

// ============ logits: inverted-index + single coalesced stream of out_emb ============

__global__ __launch_bounds__(256) void zerocnt_kernel(int* __restrict__ counts) {
    int i = blockIdx.x * 256 + threadIdx.x;
    if (i < VPAD_) counts[i] = 0;
}

// histogram + write mask/new_targets (order-independent)
__global__ __launch_bounds__(256) void hist_kernel(
        const int* __restrict__ pos_t, const int* __restrict__ pos_l,
        const int* __restrict__ neg_t, const int* __restrict__ neg_l,
        int* __restrict__ counts, float* __restrict__ dout) {
    int i = blockIdx.x * 256 + threadIdx.x;
    if (i >= B_ * TT_) return;
    int b = i / TT_, t = i - b * TT_;
    int tgt, valid, ispos;
    if (t < TPOS_) { tgt = pos_t[b * TPOS_ + t]; valid = (t < pos_l[b]); ispos = 1; }
    else { int tn = t - TPOS_; tgt = neg_t[b * TNEG_ + tn]; valid = (tn < neg_l[b]); ispos = 0; }
    atomicAdd(&counts[tgt], 1);
    dout[(size_t)B_ * TT_ + i] = valid ? 1.0f : 0.0f;
    dout[2 * (size_t)B_ * TT_ + i] = (valid && ispos) ? 1.0f : 0.0f;
}

// single-block exclusive scan over VPAD_ counts -> offs and cursor
__global__ __launch_bounds__(1024) void scan_kernel(
        const int* __restrict__ counts, int* __restrict__ offs, int* __restrict__ cursor) {
    __shared__ int part[1024];
    int t = threadIdx.x;
    const int per = VPAD_ / 1024;   // 49
    int base = t * per;
    int s = 0;
    for (int j = 0; j < per; j++) s += counts[base + j];
    part[t] = s;
    __syncthreads();
    // inclusive Hillis-Steele scan
    for (int o = 1; o < 1024; o <<= 1) {
        int v = (t >= o) ? part[t - o] : 0;
        __syncthreads();
        part[t] += v;
        __syncthreads();
    }
    int run = part[t] - s;          // exclusive prefix for this chunk
    for (int j = 0; j < per; j++) {
        offs[base + j] = run;
        cursor[base + j] = run;
        run += counts[base + j];
    }
}

// fill entries: entries[cursor[tgt]++] = flat index i
__global__ __launch_bounds__(256) void fill_kernel(
        const int* __restrict__ pos_t, const int* __restrict__ neg_t,
        int* __restrict__ cursor, int* __restrict__ entries) {
    int i = blockIdx.x * 256 + threadIdx.x;
    if (i >= B_ * TT_) return;
    int b = i / TT_, t = i - b * TT_;
    int tgt;
    if (t < TPOS_) tgt = pos_t[b * TPOS_ + t];
    else tgt = neg_t[b * TNEG_ + t - TPOS_];
    int p = atomicAdd(&cursor[tgt], 1);
    entries[p] = i;
}

// stream out_emb rows sequentially (wave per row); dot vs L2-resident outvec
__global__ __launch_bounds__(256) void lstream_kernel(
        const float* __restrict__ out_emb, const float* __restrict__ outvec,
        const int* __restrict__ counts, const int* __restrict__ offs,
        const int* __restrict__ entries, float* __restrict__ dout) {
    int wave = threadIdx.x >> 6, lane = threadIdx.x & 63;
    int v = blockIdx.x * 4 + wave;
    if (v >= V_) return;
    int n = counts[v];
    if (n == 0) return;
    const float4* e4 = reinterpret_cast<const float4*>(out_emb + (size_t)v * 768);
    float4 r0 = e4[lane], r1 = e4[64 + lane], r2 = e4[128 + lane];
    int c0 = offs[v];
    for (int k = 0; k < n; k++) {
        int idx = entries[c0 + k];
        int b = idx / TT_;
        const float4* o4 = reinterpret_cast<const float4*>(outvec + (size_t)b * 768);
        float4 o0 = o4[lane], o1 = o4[64 + lane], o2 = o4[128 + lane];
        float acc = r0.x * o0.x + r0.y * o0.y + r0.z * o0.z + r0.w * o0.w
                  + r1.x * o1.x + r1.y * o1.y + r1.z * o1.z + r1.w * o1.w
                  + r2.x * o2.x + r2.y * o2.y + r2.z * o2.z + r2.w * o2.w;
        #pragma unroll
        for (int m = 1; m < 64; m <<= 1) acc += __shfl_xor(acc, m);
        if (lane == 0) dout[idx] = acc;
    }
}

extern "C" void kernel_launch(void* const* d_in, const int* in_sizes, int n_in,
                              void* d_out, int out_size, void* d_ws, size_t ws_size,
                              hipStream_t stream) {
    const int*   attr        = (const int*)d_in[0];
    const float* attr_tf     = (const float*)d_in[2];
    const float* attr_feat   = (const float*)d_in[3];
    const int*   attr_lens   = (const int*)d_in[4];
    const int*   attr_lens_u = (const int*)d_in[5];
    const int*   user_ids    = (const int*)d_in[7];
    const int*   item_ids    = (const int*)d_in[8];
    const int*   pos_targets = (const int*)d_in[9];
    const int*   pos_lens    = (const int*)d_in[10];
    const int*   neg_targets = (const int*)d_in[11];
    const int*   neg_lens    = (const int*)d_in[12];
    const float* attr_emb    = (const float*)d_in[13];
    const float* user_emb    = (const float*)d_in[14];
    const float* item_emb    = (const float*)d_in[15];
    const float* out_emb     = (const float*)d_in[16];
    const float* fw_W        = (const float*)d_in[17];
    const float* fw_b        = (const float*)d_in[18];
    const float* qkv_w       = (const float*)d_in[19];
    const float* qkv_b       = (const float*)d_in[20];
    const float* attn_out_w  = (const float*)d_in[21];
    const float* attn_out_b  = (const float*)d_in[22];
    const float* ln1_s       = (const float*)d_in[23];
    const float* ln1_b       = (const float*)d_in[24];
    const float* ff1_w       = (const float*)d_in[25];
    const float* ff1_b       = (const float*)d_in[26];
    const float* ff2_w       = (const float*)d_in[27];
    const float* ff2_b       = (const float*)d_in[28];
    const float* ln2_s       = (const float*)d_in[29];
    const float* ln2_b       = (const float*)d_in[30];

    // ---- workspace plan ----
    size_t szRes = (size_t)ROWS_ * E_ * 2;
    size_t wB = (size_t)1572864 * 2;
    size_t idxB = (size_t)VPAD_ * 4 * 3 + (size_t)B_ * TT_ * 4;
    size_t fixedB = 2 * szRes + wB + idxB + (size_t)B_ * 768 * 4 + 4096 + 16384;
    int CH = 32;
    for (int ch = 1; ch <= 32; ch <<= 1) {
        if (fixedB + (size_t)(ROWS_ / ch) * 1024 * 2 <= ws_size) { CH = ch; break; }
    }
    int rowsC = ROWS_ / CH, sampC = B_ / CH;

    char* ws = (char*)d_ws;
    size_t off = 0;
    auto alloc = [&](size_t bytes) { void* pp = ws + off; off += (bytes + 255) & ~255ULL; return pp; };
    bf16_t* xb  = (bf16_t*)alloc(szRes);
    bf16_t* ob  = (bf16_t*)alloc(szRes);
    bf16_t* wq  = (bf16_t*)alloc((size_t)393216 * 2);
    bf16_t* wa  = (bf16_t*)alloc((size_t)131072 * 2);
    bf16_t* w1  = (bf16_t*)alloc((size_t)524288 * 2);
    bf16_t* w2  = (bf16_t*)alloc((size_t)524288 * 2);
    float* outvec = (float*)alloc((size_t)B_ * 768 * 4);
    float* wu     = (float*)alloc(1024);
    int* counts   = (int*)alloc((size_t)VPAD_ * 4);
    int* offs     = (int*)alloc((size_t)VPAD_ * 4);
    int* cursor   = (int*)alloc((size_t)VPAD_ * 4);
    int* entries  = (int*)alloc((size_t)B_ * TT_ * 4);
    bf16_t* chunk = (bf16_t*)alloc((size_t)rowsC * 1024 * 2);

    cvtall_kernel<<<6144, 256, 0, stream>>>(qkv_w, attn_out_w, ff1_w, ff2_w, wq, wa, w1, w2);
    embed_kernel<<<ROWS_ / 4, 256, 0, stream>>>(attr, attr_emb, xb);
    // build logits inverted index early (independent of encoder)
    zerocnt_kernel<<<(VPAD_ + 255) / 256, 256, 0, stream>>>(counts);
    hist_kernel<<<(B_ * TT_ + 255) / 256, 256, 0, stream>>>(
        pos_targets, pos_lens, neg_targets, neg_lens, counts, (float*)d_out);
    scan_kernel<<<1, 1024, 0, stream>>>(counts, offs, cursor);
    fill_kernel<<<(B_ * TT_ + 255) / 256, 256, 0, stream>>>(
        pos_targets, neg_targets, cursor, entries);

    for (int l = 0; l < 2; l++) {
        for (int c = 0; c < CH; c++) {
            size_t r0 = (size_t)c * rowsC;
            gemm8_kernel<false><<<dim3(3, rowsC / 128), 512, 0, stream>>>(
                xb + r0 * E_, wq + (size_t)l * 768 * 256, qkv_b + l * 768, chunk, rowsC, 768, 256);
            attn_kernel<<<sampC * H_, 256, 0, stream>>>(chunk, attr_lens + c * sampC, ob + r0 * E_);
        }
        gemm_ln8_kernel<<<ROWS_ / 128, 512, 0, stream>>>(
            ob, wa + (size_t)l * 256 * 256, attn_out_b + l * 256,
            ln1_s + l * 256, ln1_b + l * 256, xb, ROWS_, 256);
        for (int c = 0; c < CH; c++) {
            size_t r0 = (size_t)c * rowsC;
            gemm8_kernel<true><<<dim3(4, rowsC / 128), 512, 0, stream>>>(
                xb + r0 * E_, w1 + (size_t)l * 1024 * 256, ff1_b + l * 1024, chunk, rowsC, 1024, 256);
            gemm_ln8_kernel<<<rowsC / 128, 512, 0, stream>>>(
                chunk, w2 + (size_t)l * 256 * 1024, ff2_b + l * 256,
                ln2_s + l * 256, ln2_b + l * 256, xb + r0 * E_, rowsC, 1024);
        }
    }

    wuser_kernel<<<1, 256, 0, stream>>>(attr_feat, fw_W, fw_b, wu);
    pool_kernel<<<B_, 256, 0, stream>>>(xb, attr_tf, attr_lens, attr_lens_u, wu,
                                        user_ids, item_ids, user_emb, item_emb, outvec);
    lstream_kernel<<<(V_ + 3) / 4, 256, 0, stream>>>(
        out_emb, outvec, counts, offs, entries, (float*)d_out);
}

// Round 13
// 389.156 us; speedup vs baseline: 1.0631x; 1.0631x over previous
//
#include <hip/hip_runtime.h>
#include <hip/hip_bf16.h>

typedef __bf16 bf16_t;
typedef __bf16 bf16x8 __attribute__((ext_vector_type(8)));
typedef __bf16 bf16x4 __attribute__((ext_vector_type(4)));
typedef float f32x4 __attribute__((ext_vector_type(4)));

#define B_ 256
#define S_ 128
#define E_ 256
#define H_ 4
#define HD_ 64
#define F_ 1024
#define TPOS_ 100
#define TNEG_ 500
#define TT_ 600
#define ROWS_ (B_ * S_)   // 32768

// ---------------- all-weights fp32 -> bf16 convert (one launch) ----------------
__global__ __launch_bounds__(256) void cvtall_kernel(
        const float* __restrict__ sq, const float* __restrict__ sa,
        const float* __restrict__ s1, const float* __restrict__ s2,
        bf16_t* __restrict__ dq, bf16_t* __restrict__ da,
        bf16_t* __restrict__ d1, bf16_t* __restrict__ d2) {
    int i = blockIdx.x * 256 + threadIdx.x;
    if (i < 393216) { dq[i] = (bf16_t)sq[i]; }
    else if (i < 524288) { int j = i - 393216; da[j] = (bf16_t)sa[j]; }
    else if (i < 1048576) { int j = i - 524288; d1[j] = (bf16_t)s1[j]; }
    else { int j = i - 1048576; d2[j] = (bf16_t)s2[j]; }
}

// ---------------- embedding gather -> xb bf16 ----------------
__global__ __launch_bounds__(256) void embed_kernel(const int* __restrict__ attr,
        const float* __restrict__ emb, bf16_t* __restrict__ xb) {
    int row = blockIdx.x * 4 + (threadIdx.x >> 6);
    int lane = threadIdx.x & 63;
    int idx = attr[row];
    float4 v = reinterpret_cast<const float4*>(emb + (size_t)idx * E_)[lane];
    bf16x4 o; o[0] = (bf16_t)v.x; o[1] = (bf16_t)v.y; o[2] = (bf16_t)v.z; o[3] = (bf16_t)v.w;
    *reinterpret_cast<bf16x4*>(xb + (size_t)row * E_ + lane * 4) = o;
}

// ---------------- GEMM 8-wave, triple-buffer + counted vmcnt (T4 minimal port) ----------
// block 512 thr = 8 waves (2m x 4n), tile 128x256, BK=32, depth-2 prefetch,
// one raw s_barrier per K-step; vmcnt(3) = 1 in-flight STAGE (3 loads/wave).
template<bool RELU>
__global__ __launch_bounds__(512) void gemm8_kernel(
        const bf16_t* __restrict__ A, const bf16_t* __restrict__ W,
        const float* __restrict__ bias, bf16_t* __restrict__ outB, int M, int N, int K) {
    __shared__ bf16_t lA[3][128 * 32];
    __shared__ bf16_t lB[3][256 * 32];
    int tid = threadIdx.x;
    int wave = tid >> 6, lane = tid & 63;
    int wm = wave >> 2, wn = wave & 3;
    int mBase = blockIdx.y * 128;
    int nBase = blockIdx.x * 256;
    int r16 = lane & 15, kg = lane >> 4;

    const bf16_t* gA = A + (size_t)(mBase + (tid >> 2)) * K + (tid & 3) * 8;
    const bf16_t* gB = W + (size_t)(nBase + (tid >> 2)) * K + (tid & 3) * 8;

    f32x4 acc[4][4] = {};

    #define STG(buf, k0) { \
        __builtin_amdgcn_global_load_lds( \
            (const __attribute__((address_space(1))) void*)(gA + (k0)), \
            (__attribute__((address_space(3))) void*)(&lA[buf][wave * 512]), 16, 0, 0); \
        _Pragma("unroll") \
        for (int iss = 0; iss < 2; iss++) { \
            __builtin_amdgcn_global_load_lds( \
                (const __attribute__((address_space(1))) void*)(gB + (size_t)iss * 128 * K + (k0)), \
                (__attribute__((address_space(3))) void*)(&lB[buf][iss * 4096 + wave * 512]), 16, 0, 0); \
        } }

    int nt = K >> 5;
    STG(0, 0);
    STG(1, 32);
    for (int t = 0; t < nt; ++t) {
        if (t + 1 < nt) { asm volatile("s_waitcnt vmcnt(3)" ::: "memory"); }
        else            { asm volatile("s_waitcnt vmcnt(0)" ::: "memory"); }
        asm volatile("s_barrier" ::: "memory");
        int cur = t % 3;
        if (t + 2 < nt) { int st = (t + 2) % 3; STG(st, (t + 2) * 32); }
        bf16x8 a[4], b[4];
        #pragma unroll
        for (int i = 0; i < 4; i++) {
            a[i] = *reinterpret_cast<const bf16x8*>(&lA[cur][(wm * 64 + i * 16 + r16) * 32 + kg * 8]);
            b[i] = *reinterpret_cast<const bf16x8*>(&lB[cur][(wn * 64 + i * 16 + r16) * 32 + kg * 8]);
        }
        #pragma unroll
        for (int mi = 0; mi < 4; mi++)
            #pragma unroll
            for (int ni = 0; ni < 4; ni++)
                acc[mi][ni] = __builtin_amdgcn_mfma_f32_16x16x32_bf16(a[mi], b[ni], acc[mi][ni], 0, 0, 0);
    }
    #undef STG

    #pragma unroll
    for (int mi = 0; mi < 4; mi++) {
        #pragma unroll
        for (int ni = 0; ni < 4; ni++) {
            int col = nBase + wn * 64 + ni * 16 + r16;
            float bv = bias[col];
            #pragma unroll
            for (int j = 0; j < 4; j++) {
                int row = mBase + wm * 64 + mi * 16 + kg * 4 + j;
                float v = acc[mi][ni][j] + bv;
                if (RELU) v = v > 0.f ? v : 0.f;
                outB[(size_t)row * N + col] = (bf16_t)v;
            }
        }
    }
}

// ------- fused GEMM + bias + residual + LayerNorm, 8-wave, triple-buffer counted -------
__global__ __launch_bounds__(512) void gemm_ln8_kernel(
        const bf16_t* __restrict__ A, const bf16_t* __restrict__ W,
        const float* __restrict__ bias, const float* __restrict__ sc,
        const float* __restrict__ bi, bf16_t* __restrict__ xb, int M, int K) {
    __shared__ bf16_t lA[3][128 * 32];
    __shared__ bf16_t lB[3][256 * 32];
    __shared__ float psum[128][4][2];
    int tid = threadIdx.x;
    int wave = tid >> 6, lane = tid & 63;
    int wm = wave >> 2, wn = wave & 3;
    int mBase = blockIdx.x * 128;
    int r16 = lane & 15, kg = lane >> 4;

    const bf16_t* gA = A + (size_t)(mBase + (tid >> 2)) * K + (tid & 3) * 8;
    const bf16_t* gB = W + (size_t)((tid >> 2)) * K + (tid & 3) * 8;

    f32x4 acc[4][4] = {};

    #define STG2(buf, k0) { \
        __builtin_amdgcn_global_load_lds( \
            (const __attribute__((address_space(1))) void*)(gA + (k0)), \
            (__attribute__((address_space(3))) void*)(&lA[buf][wave * 512]), 16, 0, 0); \
        _Pragma("unroll") \
        for (int iss = 0; iss < 2; iss++) { \
            __builtin_amdgcn_global_load_lds( \
                (const __attribute__((address_space(1))) void*)(gB + (size_t)iss * 128 * K + (k0)), \
                (__attribute__((address_space(3))) void*)(&lB[buf][iss * 4096 + wave * 512]), 16, 0, 0); \
        } }

    int nt = K >> 5;
    STG2(0, 0);
    STG2(1, 32);
    for (int t = 0; t < nt; ++t) {
        if (t + 1 < nt) { asm volatile("s_waitcnt vmcnt(3)" ::: "memory"); }
        else            { asm volatile("s_waitcnt vmcnt(0)" ::: "memory"); }
        asm volatile("s_barrier" ::: "memory");
        int cur = t % 3;
        if (t + 2 < nt) { int st = (t + 2) % 3; STG2(st, (t + 2) * 32); }
        bf16x8 a[4], b[4];
        #pragma unroll
        for (int i = 0; i < 4; i++) {
            a[i] = *reinterpret_cast<const bf16x8*>(&lA[cur][(wm * 64 + i * 16 + r16) * 32 + kg * 8]);
            b[i] = *reinterpret_cast<const bf16x8*>(&lB[cur][(wn * 64 + i * 16 + r16) * 32 + kg * 8]);
        }
        #pragma unroll
        for (int mi = 0; mi < 4; mi++)
            #pragma unroll
            for (int ni = 0; ni < 4; ni++)
                acc[mi][ni] = __builtin_amdgcn_mfma_f32_16x16x32_bf16(a[mi], b[ni], acc[mi][ni], 0, 0, 0);
    }
    #undef STG2

    float bv[4];
    #pragma unroll
    for (int ni = 0; ni < 4; ni++) bv[ni] = bias[wn * 64 + ni * 16 + r16];
    #pragma unroll
    for (int mi = 0; mi < 4; mi++) {
        #pragma unroll
        for (int j = 0; j < 4; j++) {
            int rl = wm * 64 + mi * 16 + kg * 4 + j;
            const bf16_t* rrow = xb + (size_t)(mBase + rl) * 256;
            float s = 0.f, q = 0.f;
            #pragma unroll
            for (int ni = 0; ni < 4; ni++) {
                int col = wn * 64 + ni * 16 + r16;
                float v = acc[mi][ni][j] + bv[ni] + (float)rrow[col];
                acc[mi][ni][j] = v;
                s += v; q += v * v;
            }
            #pragma unroll
            for (int m = 1; m < 16; m <<= 1) { s += __shfl_xor(s, m); q += __shfl_xor(q, m); }
            if (r16 == 0) { psum[rl][wn][0] = s; psum[rl][wn][1] = q; }
        }
    }
    __syncthreads();
    #pragma unroll
    for (int mi = 0; mi < 4; mi++) {
        #pragma unroll
        for (int j = 0; j < 4; j++) {
            int rl = wm * 64 + mi * 16 + kg * 4 + j;
            float s = psum[rl][0][0] + psum[rl][1][0] + psum[rl][2][0] + psum[rl][3][0];
            float qq = psum[rl][0][1] + psum[rl][1][1] + psum[rl][2][1] + psum[rl][3][1];
            float mean = s * (1.0f / 256.0f);
            float var = qq * (1.0f / 256.0f) - mean * mean;
            float inv = rsqrtf(var + 1e-5f);
            bf16_t* orow = xb + (size_t)(mBase + rl) * 256;
            #pragma unroll
            for (int ni = 0; ni < 4; ni++) {
                int col = wn * 64 + ni * 16 + r16;
                float o = (acc[mi][ni][j] - mean) * inv * sc[col] + bi[col];
                orow[col] = (bf16_t)o;
            }
        }
    }
}

// ---------------- fused attention per (b,h); V transposed in-kernel via LDS ----------------
__global__ __launch_bounds__(256) void attn_kernel(const bf16_t* __restrict__ qkv,
        const int* __restrict__ lens, bf16_t* __restrict__ out) {
    __shared__ bf16_t p[S_][S_ + 8];
    __shared__ bf16_t vl[HD_][S_ + 8];
    int bh = blockIdx.x; int b = bh >> 2, h = bh & 3;
    int wave = threadIdx.x >> 6, lane = threadIdx.x & 63;
    int r16 = lane & 15, kg = lane >> 4;
    int q0 = wave * 32;
    int len = lens[b];
    const bf16_t* qbase = qkv + (size_t)b * S_ * 768;

    {
        int sl = (wave & 1) * 64 + lane;
        const bf16_t* vsrc = qbase + (size_t)sl * 768 + 512 + h * HD_;
        #pragma unroll
        for (int pass = 0; pass < 4; pass++) {
            int d0 = (pass * 2 + (wave >> 1)) * 8;
            bf16x8 v = *reinterpret_cast<const bf16x8*>(vsrc + d0);
            #pragma unroll
            for (int j = 0; j < 8; j++) vl[d0 + j][sl] = v[j];
        }
    }

    f32x4 acc[2][8] = {};
    #pragma unroll
    for (int ks = 0; ks < 2; ks++) {
        int kOff = h * HD_ + ks * 32 + kg * 8;
        bf16x8 a[2], bb[8];
        #pragma unroll
        for (int mi = 0; mi < 2; mi++)
            a[mi] = *reinterpret_cast<const bf16x8*>(qbase + (size_t)(q0 + mi * 16 + r16) * 768 + kOff);
        #pragma unroll
        for (int ni = 0; ni < 8; ni++)
            bb[ni] = *reinterpret_cast<const bf16x8*>(qbase + (size_t)(ni * 16 + r16) * 768 + 256 + kOff);
        #pragma unroll
        for (int mi = 0; mi < 2; mi++)
            #pragma unroll
            for (int ni = 0; ni < 8; ni++)
                acc[mi][ni] = __builtin_amdgcn_mfma_f32_16x16x32_bf16(a[mi], bb[ni], acc[mi][ni], 0, 0, 0);
    }
    #pragma unroll
    for (int mi = 0; mi < 2; mi++) {
        #pragma unroll
        for (int j = 0; j < 4; j++) {
            float vals[8]; float mx = -1e30f;
            #pragma unroll
            for (int ni = 0; ni < 8; ni++) {
                int kp = ni * 16 + r16;
                float v = acc[mi][ni][j] * 0.125f;
                vals[ni] = (kp < len) ? v : -1e30f;
                mx = fmaxf(mx, vals[ni]);
            }
            #pragma unroll
            for (int m = 1; m < 16; m <<= 1) mx = fmaxf(mx, __shfl_xor(mx, m));
            float sum = 0.f;
            #pragma unroll
            for (int ni = 0; ni < 8; ni++) {
                vals[ni] = (vals[ni] > -1e29f) ? __expf(vals[ni] - mx) : 0.f;
                sum += vals[ni];
            }
            #pragma unroll
            for (int m = 1; m < 16; m <<= 1) sum += __shfl_xor(sum, m);
            float inv = 1.0f / sum;
            int row = q0 + mi * 16 + kg * 4 + j;
            #pragma unroll
            for (int ni = 0; ni < 8; ni++)
                p[row][ni * 16 + r16] = (bf16_t)(vals[ni] * inv);
        }
    }
    __syncthreads();
    f32x4 acc2[2][4] = {};
    #pragma unroll
    for (int ks = 0; ks < 4; ks++) {
        int k = ks * 32 + kg * 8;
        bf16x8 a[2], bb[4];
        #pragma unroll
        for (int mi = 0; mi < 2; mi++)
            a[mi] = *reinterpret_cast<const bf16x8*>(&p[q0 + mi * 16 + r16][k]);
        #pragma unroll
        for (int ni = 0; ni < 4; ni++)
            bb[ni] = *reinterpret_cast<const bf16x8*>(&vl[ni * 16 + r16][k]);
        #pragma unroll
        for (int mi = 0; mi < 2; mi++)
            #pragma unroll
            for (int ni = 0; ni < 4; ni++)
                acc2[mi][ni] = __builtin_amdgcn_mfma_f32_16x16x32_bf16(a[mi], bb[ni], acc2[mi][ni], 0, 0, 0);
    }
    #pragma unroll
    for (int mi = 0; mi < 2; mi++)
        #pragma unroll
        for (int ni = 0; ni < 4; ni++)
            #pragma unroll
            for (int j = 0; j < 4; j++) {
                int q = q0 + mi * 16 + kg * 4 + j;
                int d = ni * 16 + r16;
                out[((size_t)b * S_ + q) * E_ + h * HD_ + d] = (bf16_t)acc2[mi][ni][j];
            }
}

// ---------------- pooling + concat (wuser folded in) -> outvec[B,768] fp32 ----------------
__global__ __launch_bounds__(256) void pool_kernel(
        const bf16_t* __restrict__ xb, const float* __restrict__ attr_tf,
        const int* __restrict__ lens, const int* __restrict__ lens_user,
        const float* __restrict__ feat, const float* __restrict__ fwW,
        const float* __restrict__ fwb,
        const int* __restrict__ uid, const int* __restrict__ iid,
        const float* __restrict__ user_emb, const float* __restrict__ item_emb,
        float* __restrict__ outvec) {
    int b = blockIdx.x, t = threadIdx.x;
    __shared__ float wrow[S_];
    // per-sample sigmoid weight (all threads compute redundantly; 13 FMAs)
    float z = fwb[0];
    #pragma unroll
    for (int i = 0; i < 13; i++) z += feat[b * 13 + i] * fwW[i];
    float wub = 1.f / (1.f + __expf(-z));
    if (t < S_) {
        float w = (t < lens[b]) ? attr_tf[b * S_ + t] : 0.f;
        float side = (t < lens_user[b]) ? wub : (1.f - wub);
        wrow[t] = w * side;
    }
    __syncthreads();
    float acc = 0.f;
    const bf16_t* xr = xb + (size_t)b * S_ * E_ + t;
    #pragma unroll 4
    for (int s = 0; s < S_; s++) acc += wrow[s] * (float)xr[(size_t)s * E_];
    outvec[b * 768 + 256 + t] = acc;
    outvec[b * 768 + t] = user_emb[(size_t)uid[b] * E_ + t];
    outvec[b * 768 + 512 + t] = item_emb[(size_t)iid[b] * E_ + t];
}

// ---------------- logits + mask + new_targets -> d_out (fp32); 2 targets per wave ----
__global__ __launch_bounds__(256) void logits_kernel(
        const float* __restrict__ outvec, const float* __restrict__ out_emb,
        const int* __restrict__ pos_t, const int* __restrict__ pos_l,
        const int* __restrict__ neg_t, const int* __restrict__ neg_l,
        float* __restrict__ dout) {
    int gg = blockIdx.x * 4 + (threadIdx.x >> 6);
    int lane = threadIdx.x & 63;
    int b = gg / (TT_ / 2);
    int u = gg - b * (TT_ / 2);
    int pl = pos_l[b], nl = neg_l[b];
    int t0 = u * 2, t1 = u * 2 + 1;

    int tgt0, tgt1, valid0, valid1, ispos0, ispos1;
    if (t0 < TPOS_) { tgt0 = pos_t[b * TPOS_ + t0]; valid0 = (t0 < pl); ispos0 = 1; }
    else { int tn = t0 - TPOS_; tgt0 = neg_t[b * TNEG_ + tn]; valid0 = (tn < nl); ispos0 = 0; }
    if (t1 < TPOS_) { tgt1 = pos_t[b * TPOS_ + t1]; valid1 = (t1 < pl); ispos1 = 1; }
    else { int tn = t1 - TPOS_; tgt1 = neg_t[b * TNEG_ + tn]; valid1 = (tn < nl); ispos1 = 0; }

    const float4* e0 = reinterpret_cast<const float4*>(out_emb + (size_t)tgt0 * 768);
    const float4* e1 = reinterpret_cast<const float4*>(out_emb + (size_t)tgt1 * 768);
    const float4* o4 = reinterpret_cast<const float4*>(outvec + (size_t)b * 768);
    float acc0 = 0.f, acc1 = 0.f;
    #pragma unroll
    for (int c = 0; c < 3; c++) {
        float4 a0 = e0[c * 64 + lane];
        float4 a1 = e1[c * 64 + lane];
        float4 o = o4[c * 64 + lane];
        acc0 += a0.x * o.x + a0.y * o.y + a0.z * o.z + a0.w * o.w;
        acc1 += a1.x * o.x + a1.y * o.y + a1.z * o.z + a1.w * o.w;
    }
    #pragma unroll
    for (int m = 1; m < 64; m <<= 1) { acc0 += __shfl_xor(acc0, m); acc1 += __shfl_xor(acc1, m); }
    if (lane == 0) {
        size_t i0 = (size_t)b * TT_ + t0;
        dout[i0] = acc0;
        dout[i0 + 1] = acc1;
        dout[(size_t)B_ * TT_ + i0] = valid0 ? 1.0f : 0.0f;
        dout[(size_t)B_ * TT_ + i0 + 1] = valid1 ? 1.0f : 0.0f;
        dout[2 * (size_t)B_ * TT_ + i0] = (valid0 && ispos0) ? 1.0f : 0.0f;
        dout[2 * (size_t)B_ * TT_ + i0 + 1] = (valid1 && ispos1) ? 1.0f : 0.0f;
    }
}

extern "C" void kernel_launch(void* const* d_in, const int* in_sizes, int n_in,
                              void* d_out, int out_size, void* d_ws, size_t ws_size,
                              hipStream_t stream) {
    const int*   attr        = (const int*)d_in[0];
    const float* attr_tf     = (const float*)d_in[2];
    const float* attr_feat   = (const float*)d_in[3];
    const int*   attr_lens   = (const int*)d_in[4];
    const int*   attr_lens_u = (const int*)d_in[5];
    const int*   user_ids    = (const int*)d_in[7];
    const int*   item_ids    = (const int*)d_in[8];
    const int*   pos_targets = (const int*)d_in[9];
    const int*   pos_lens    = (const int*)d_in[10];
    const int*   neg_targets = (const int*)d_in[11];
    const int*   neg_lens    = (const int*)d_in[12];
    const float* attr_emb    = (const float*)d_in[13];
    const float* user_emb    = (const float*)d_in[14];
    const float* item_emb    = (const float*)d_in[15];
    const float* out_emb     = (const float*)d_in[16];
    const float* fw_W        = (const float*)d_in[17];
    const float* fw_b        = (const float*)d_in[18];
    const float* qkv_w       = (const float*)d_in[19];
    const float* qkv_b       = (const float*)d_in[20];
    const float* attn_out_w  = (const float*)d_in[21];
    const float* attn_out_b  = (const float*)d_in[22];
    const float* ln1_s       = (const float*)d_in[23];
    const float* ln1_b       = (const float*)d_in[24];
    const float* ff1_w       = (const float*)d_in[25];
    const float* ff1_b       = (const float*)d_in[26];
    const float* ff2_w       = (const float*)d_in[27];
    const float* ff2_b       = (const float*)d_in[28];
    const float* ln2_s       = (const float*)d_in[29];
    const float* ln2_b       = (const float*)d_in[30];

    // ---- workspace plan ----
    size_t szRes = (size_t)ROWS_ * E_ * 2;
    size_t wB = (size_t)1572864 * 2;
    size_t fixedB = 2 * szRes + wB + (size_t)B_ * 768 * 4 + 4096 + 16384;
    int CH = 32;
    for (int ch = 1; ch <= 32; ch <<= 1) {
        if (fixedB + (size_t)(ROWS_ / ch) * 1024 * 2 <= ws_size) { CH = ch; break; }
    }
    int rowsC = ROWS_ / CH, sampC = B_ / CH;

    char* ws = (char*)d_ws;
    size_t off = 0;
    auto alloc = [&](size_t bytes) { void* pp = ws + off; off += (bytes + 255) & ~255ULL; return pp; };
    bf16_t* xb  = (bf16_t*)alloc(szRes);
    bf16_t* ob  = (bf16_t*)alloc(szRes);
    bf16_t* wq  = (bf16_t*)alloc((size_t)393216 * 2);
    bf16_t* wa  = (bf16_t*)alloc((size_t)131072 * 2);
    bf16_t* w1  = (bf16_t*)alloc((size_t)524288 * 2);
    bf16_t* w2  = (bf16_t*)alloc((size_t)524288 * 2);
    float* outvec = (float*)alloc((size_t)B_ * 768 * 4);
    bf16_t* chunk = (bf16_t*)alloc((size_t)rowsC * 1024 * 2);

    cvtall_kernel<<<6144, 256, 0, stream>>>(qkv_w, attn_out_w, ff1_w, ff2_w, wq, wa, w1, w2);
    embed_kernel<<<ROWS_ / 4, 256, 0, stream>>>(attr, attr_emb, xb);

    for (int l = 0; l < 2; l++) {
        for (int c = 0; c < CH; c++) {
            size_t r0 = (size_t)c * rowsC;
            gemm8_kernel<false><<<dim3(3, rowsC / 128), 512, 0, stream>>>(
                xb + r0 * E_, wq + (size_t)l * 768 * 256, qkv_b + l * 768, chunk, rowsC, 768, 256);
            attn_kernel<<<sampC * H_, 256, 0, stream>>>(chunk, attr_lens + c * sampC, ob + r0 * E_);
        }
        gemm_ln8_kernel<<<ROWS_ / 128, 512, 0, stream>>>(
            ob, wa + (size_t)l * 256 * 256, attn_out_b + l * 256,
            ln1_s + l * 256, ln1_b + l * 256, xb, ROWS_, 256);
        for (int c = 0; c < CH; c++) {
            size_t r0 = (size_t)c * rowsC;
            gemm8_kernel<true><<<dim3(4, rowsC / 128), 512, 0, stream>>>(
                xb + r0 * E_, w1 + (size_t)l * 1024 * 256, ff1_b + l * 1024, chunk, rowsC, 1024, 256);
            gemm_ln8_kernel<<<rowsC / 128, 512, 0, stream>>>(
                chunk, w2 + (size_t)l * 256 * 1024, ff2_b + l * 256,
                ln2_s + l * 256, ln2_b + l * 256, xb + r0 * E_, rowsC, 1024);
        }
    }

    pool_kernel<<<B_, 256, 0, stream>>>(xb, attr_tf, attr_lens, attr_lens_u,
                                        attr_feat, fw_W, fw_b,
                                        user_ids, item_ids, user_emb, item_emb, outvec);
    logits_kernel<<<B_ * TT_ / 8, 256, 0, stream>>>(outvec, out_emb, pos_targets, pos_lens,
                                                    neg_targets, neg_lens, (float*)d_out);
}

// Round 14
// 379.842 us; speedup vs baseline: 1.0891x; 1.0245x over previous
//
#include <hip/hip_runtime.h>
#include <hip/hip_bf16.h>

typedef __bf16 bf16_t;
typedef __bf16 bf16x8 __attribute__((ext_vector_type(8)));
typedef __bf16 bf16x4 __attribute__((ext_vector_type(4)));
typedef float f32x4 __attribute__((ext_vector_type(4)));

#define B_ 256
#define S_ 128
#define E_ 256
#define H_ 4
#define HD_ 64
#define F_ 1024
#define TPOS_ 100
#define TNEG_ 500
#define TT_ 600
#define ROWS_ (B_ * S_)   // 32768
#define PPAD_ (S_ + 4)    // 132: row stride 264B = 66 dw == 2 (mod 32) -> 2-way banks

// ---------------- all-weights fp32 -> bf16 convert (vectorized x8, one launch) ----------
// total 1,572,864 elems = 196,608 threads of 8
__global__ __launch_bounds__(256) void cvtall_kernel(
        const float* __restrict__ sq, const float* __restrict__ sa,
        const float* __restrict__ s1, const float* __restrict__ s2,
        bf16_t* __restrict__ dq, bf16_t* __restrict__ da,
        bf16_t* __restrict__ d1, bf16_t* __restrict__ d2) {
    int i = (blockIdx.x * 256 + threadIdx.x) * 8;
    const float* src; bf16_t* dst; int j;
    if (i < 393216) { src = sq; dst = dq; j = i; }
    else if (i < 524288) { src = sa; dst = da; j = i - 393216; }
    else if (i < 1048576) { src = s1; dst = d1; j = i - 524288; }
    else { src = s2; dst = d2; j = i - 1048576; }
    float4 v0 = reinterpret_cast<const float4*>(src + j)[0];
    float4 v1 = reinterpret_cast<const float4*>(src + j)[1];
    bf16x8 o;
    o[0] = (bf16_t)v0.x; o[1] = (bf16_t)v0.y; o[2] = (bf16_t)v0.z; o[3] = (bf16_t)v0.w;
    o[4] = (bf16_t)v1.x; o[5] = (bf16_t)v1.y; o[6] = (bf16_t)v1.z; o[7] = (bf16_t)v1.w;
    *reinterpret_cast<bf16x8*>(dst + j) = o;
}

// ---------------- embedding gather -> xb bf16 ----------------
__global__ __launch_bounds__(256) void embed_kernel(const int* __restrict__ attr,
        const float* __restrict__ emb, bf16_t* __restrict__ xb) {
    int row = blockIdx.x * 4 + (threadIdx.x >> 6);
    int lane = threadIdx.x & 63;
    int idx = attr[row];
    float4 v = reinterpret_cast<const float4*>(emb + (size_t)idx * E_)[lane];
    bf16x4 o; o[0] = (bf16_t)v.x; o[1] = (bf16_t)v.y; o[2] = (bf16_t)v.z; o[3] = (bf16_t)v.w;
    *reinterpret_cast<bf16x4*>(xb + (size_t)row * E_ + lane * 4) = o;
}

// ---------------- GEMM 8-wave (r11 measured-best): tile 128x256, BK=32, dbuf ----------
template<bool RELU>
__global__ __launch_bounds__(512) void gemm8_kernel(
        const bf16_t* __restrict__ A, const bf16_t* __restrict__ W,
        const float* __restrict__ bias, bf16_t* __restrict__ outB, int M, int N, int K) {
    __shared__ bf16_t lA[2][128 * 32];
    __shared__ bf16_t lB[2][256 * 32];
    int tid = threadIdx.x;
    int wave = tid >> 6, lane = tid & 63;
    int wm = wave >> 2, wn = wave & 3;
    int mBase = blockIdx.y * 128;
    int nBase = blockIdx.x * 256;
    int r16 = lane & 15, kg = lane >> 4;

    const bf16_t* gA = A + (size_t)(mBase + (tid >> 2)) * K + (tid & 3) * 8;
    const bf16_t* gB = W + (size_t)(nBase + (tid >> 2)) * K + (tid & 3) * 8;

    f32x4 acc[4][4] = {};

    #define STG(buf, k0) { \
        __builtin_amdgcn_global_load_lds( \
            (const __attribute__((address_space(1))) void*)(gA + (k0)), \
            (__attribute__((address_space(3))) void*)(&lA[buf][wave * 512]), 16, 0, 0); \
        _Pragma("unroll") \
        for (int iss = 0; iss < 2; iss++) { \
            __builtin_amdgcn_global_load_lds( \
                (const __attribute__((address_space(1))) void*)(gB + (size_t)iss * 128 * K + (k0)), \
                (__attribute__((address_space(3))) void*)(&lB[buf][iss * 4096 + wave * 512]), 16, 0, 0); \
        } }

    STG(0, 0);
    int cur = 0;
    for (int k0 = 0; k0 < K; k0 += 32) {
        __syncthreads();
        if (k0 + 32 < K) STG(cur ^ 1, k0 + 32);
        bf16x8 a[4], b[4];
        #pragma unroll
        for (int i = 0; i < 4; i++) {
            a[i] = *reinterpret_cast<const bf16x8*>(&lA[cur][(wm * 64 + i * 16 + r16) * 32 + kg * 8]);
            b[i] = *reinterpret_cast<const bf16x8*>(&lB[cur][(wn * 64 + i * 16 + r16) * 32 + kg * 8]);
        }
        #pragma unroll
        for (int mi = 0; mi < 4; mi++)
            #pragma unroll
            for (int ni = 0; ni < 4; ni++)
                acc[mi][ni] = __builtin_amdgcn_mfma_f32_16x16x32_bf16(a[mi], b[ni], acc[mi][ni], 0, 0, 0);
        cur ^= 1;
    }
    #undef STG

    #pragma unroll
    for (int mi = 0; mi < 4; mi++) {
        #pragma unroll
        for (int ni = 0; ni < 4; ni++) {
            int col = nBase + wn * 64 + ni * 16 + r16;
            float bv = bias[col];
            #pragma unroll
            for (int j = 0; j < 4; j++) {
                int row = mBase + wm * 64 + mi * 16 + kg * 4 + j;
                float v = acc[mi][ni][j] + bv;
                if (RELU) v = v > 0.f ? v : 0.f;
                outB[(size_t)row * N + col] = (bf16_t)v;
            }
        }
    }
}

// ---------------- fused GEMM + bias + residual + LayerNorm, 8-wave (N=256), dbuf -------
__global__ __launch_bounds__(512) void gemm_ln8_kernel(
        const bf16_t* __restrict__ A, const bf16_t* __restrict__ W,
        const float* __restrict__ bias, const float* __restrict__ sc,
        const float* __restrict__ bi, bf16_t* __restrict__ xb, int M, int K) {
    __shared__ bf16_t lA[2][128 * 32];
    __shared__ bf16_t lB[2][256 * 32];
    __shared__ float psum[128][4][2];
    int tid = threadIdx.x;
    int wave = tid >> 6, lane = tid & 63;
    int wm = wave >> 2, wn = wave & 3;
    int mBase = blockIdx.x * 128;
    int r16 = lane & 15, kg = lane >> 4;

    const bf16_t* gA = A + (size_t)(mBase + (tid >> 2)) * K + (tid & 3) * 8;
    const bf16_t* gB = W + (size_t)((tid >> 2)) * K + (tid & 3) * 8;

    f32x4 acc[4][4] = {};

    #define STG2(buf, k0) { \
        __builtin_amdgcn_global_load_lds( \
            (const __attribute__((address_space(1))) void*)(gA + (k0)), \
            (__attribute__((address_space(3))) void*)(&lA[buf][wave * 512]), 16, 0, 0); \
        _Pragma("unroll") \
        for (int iss = 0; iss < 2; iss++) { \
            __builtin_amdgcn_global_load_lds( \
                (const __attribute__((address_space(1))) void*)(gB + (size_t)iss * 128 * K + (k0)), \
                (__attribute__((address_space(3))) void*)(&lB[buf][iss * 4096 + wave * 512]), 16, 0, 0); \
        } }

    STG2(0, 0);
    int cur = 0;
    for (int k0 = 0; k0 < K; k0 += 32) {
        __syncthreads();
        if (k0 + 32 < K) STG2(cur ^ 1, k0 + 32);
        bf16x8 a[4], b[4];
        #pragma unroll
        for (int i = 0; i < 4; i++) {
            a[i] = *reinterpret_cast<const bf16x8*>(&lA[cur][(wm * 64 + i * 16 + r16) * 32 + kg * 8]);
            b[i] = *reinterpret_cast<const bf16x8*>(&lB[cur][(wn * 64 + i * 16 + r16) * 32 + kg * 8]);
        }
        #pragma unroll
        for (int mi = 0; mi < 4; mi++)
            #pragma unroll
            for (int ni = 0; ni < 4; ni++)
                acc[mi][ni] = __builtin_amdgcn_mfma_f32_16x16x32_bf16(a[mi], b[ni], acc[mi][ni], 0, 0, 0);
        cur ^= 1;
    }
    #undef STG2

    float bv[4];
    #pragma unroll
    for (int ni = 0; ni < 4; ni++) bv[ni] = bias[wn * 64 + ni * 16 + r16];
    #pragma unroll
    for (int mi = 0; mi < 4; mi++) {
        #pragma unroll
        for (int j = 0; j < 4; j++) {
            int rl = wm * 64 + mi * 16 + kg * 4 + j;
            const bf16_t* rrow = xb + (size_t)(mBase + rl) * 256;
            float s = 0.f, q = 0.f;
            #pragma unroll
            for (int ni = 0; ni < 4; ni++) {
                int col = wn * 64 + ni * 16 + r16;
                float v = acc[mi][ni][j] + bv[ni] + (float)rrow[col];
                acc[mi][ni][j] = v;
                s += v; q += v * v;
            }
            #pragma unroll
            for (int m = 1; m < 16; m <<= 1) { s += __shfl_xor(s, m); q += __shfl_xor(q, m); }
            if (r16 == 0) { psum[rl][wn][0] = s; psum[rl][wn][1] = q; }
        }
    }
    __syncthreads();
    #pragma unroll
    for (int mi = 0; mi < 4; mi++) {
        #pragma unroll
        for (int j = 0; j < 4; j++) {
            int rl = wm * 64 + mi * 16 + kg * 4 + j;
            float s = psum[rl][0][0] + psum[rl][1][0] + psum[rl][2][0] + psum[rl][3][0];
            float qq = psum[rl][0][1] + psum[rl][1][1] + psum[rl][2][1] + psum[rl][3][1];
            float mean = s * (1.0f / 256.0f);
            float var = qq * (1.0f / 256.0f) - mean * mean;
            float inv = rsqrtf(var + 1e-5f);
            bf16_t* orow = xb + (size_t)(mBase + rl) * 256;
            #pragma unroll
            for (int ni = 0; ni < 4; ni++) {
                int col = wn * 64 + ni * 16 + r16;
                float o = (acc[mi][ni][j] - mean) * inv * sc[col] + bi[col];
                orow[col] = (bf16_t)o;
            }
        }
    }
}

// ---------------- fused attention per (b,h): pad +4 (2-way banks) + setprio ----------------
__global__ __launch_bounds__(256) void attn_kernel(const bf16_t* __restrict__ qkv,
        const int* __restrict__ lens, bf16_t* __restrict__ out) {
    __shared__ bf16_t p[S_][PPAD_];
    __shared__ bf16_t vl[HD_][PPAD_];
    int bh = blockIdx.x; int b = bh >> 2, h = bh & 3;
    int wave = threadIdx.x >> 6, lane = threadIdx.x & 63;
    int r16 = lane & 15, kg = lane >> 4;
    int q0 = wave * 32;
    int len = lens[b];
    const bf16_t* qbase = qkv + (size_t)b * S_ * 768;

    {
        int sl = (wave & 1) * 64 + lane;
        const bf16_t* vsrc = qbase + (size_t)sl * 768 + 512 + h * HD_;
        #pragma unroll
        for (int pass = 0; pass < 4; pass++) {
            int d0 = (pass * 2 + (wave >> 1)) * 8;
            bf16x8 v = *reinterpret_cast<const bf16x8*>(vsrc + d0);
            #pragma unroll
            for (int j = 0; j < 8; j++) vl[d0 + j][sl] = v[j];
        }
    }

    f32x4 acc[2][8] = {};
    #pragma unroll
    for (int ks = 0; ks < 2; ks++) {
        int kOff = h * HD_ + ks * 32 + kg * 8;
        bf16x8 a[2], bb[8];
        #pragma unroll
        for (int mi = 0; mi < 2; mi++)
            a[mi] = *reinterpret_cast<const bf16x8*>(qbase + (size_t)(q0 + mi * 16 + r16) * 768 + kOff);
        #pragma unroll
        for (int ni = 0; ni < 8; ni++)
            bb[ni] = *reinterpret_cast<const bf16x8*>(qbase + (size_t)(ni * 16 + r16) * 768 + 256 + kOff);
        __builtin_amdgcn_s_setprio(1);
        #pragma unroll
        for (int mi = 0; mi < 2; mi++)
            #pragma unroll
            for (int ni = 0; ni < 8; ni++)
                acc[mi][ni] = __builtin_amdgcn_mfma_f32_16x16x32_bf16(a[mi], bb[ni], acc[mi][ni], 0, 0, 0);
        __builtin_amdgcn_s_setprio(0);
    }
    #pragma unroll
    for (int mi = 0; mi < 2; mi++) {
        #pragma unroll
        for (int j = 0; j < 4; j++) {
            float vals[8]; float mx = -1e30f;
            #pragma unroll
            for (int ni = 0; ni < 8; ni++) {
                int kp = ni * 16 + r16;
                float v = acc[mi][ni][j] * 0.125f;
                vals[ni] = (kp < len) ? v : -1e30f;
                mx = fmaxf(mx, vals[ni]);
            }
            #pragma unroll
            for (int m = 1; m < 16; m <<= 1) mx = fmaxf(mx, __shfl_xor(mx, m));
            float sum = 0.f;
            #pragma unroll
            for (int ni = 0; ni < 8; ni++) {
                vals[ni] = (vals[ni] > -1e29f) ? __expf(vals[ni] - mx) : 0.f;
                sum += vals[ni];
            }
            #pragma unroll
            for (int m = 1; m < 16; m <<= 1) sum += __shfl_xor(sum, m);
            float inv = 1.0f / sum;
            int row = q0 + mi * 16 + kg * 4 + j;
            #pragma unroll
            for (int ni = 0; ni < 8; ni++)
                p[row][ni * 16 + r16] = (bf16_t)(vals[ni] * inv);
        }
    }
    __syncthreads();
    f32x4 acc2[2][4] = {};
    #pragma unroll
    for (int ks = 0; ks < 4; ks++) {
        int k = ks * 32 + kg * 8;
        bf16x8 a[2], bb[4];
        #pragma unroll
        for (int mi = 0; mi < 2; mi++)
            a[mi] = *reinterpret_cast<const bf16x8*>(&p[q0 + mi * 16 + r16][k]);
        #pragma unroll
        for (int ni = 0; ni < 4; ni++)
            bb[ni] = *reinterpret_cast<const bf16x8*>(&vl[ni * 16 + r16][k]);
        __builtin_amdgcn_s_setprio(1);
        #pragma unroll
        for (int mi = 0; mi < 2; mi++)
            #pragma unroll
            for (int ni = 0; ni < 4; ni++)
                acc2[mi][ni] = __builtin_amdgcn_mfma_f32_16x16x32_bf16(a[mi], bb[ni], acc2[mi][ni], 0, 0, 0);
        __builtin_amdgcn_s_setprio(0);
    }
    #pragma unroll
    for (int mi = 0; mi < 2; mi++)
        #pragma unroll
        for (int ni = 0; ni < 4; ni++)
            #pragma unroll
            for (int j = 0; j < 4; j++) {
                int q = q0 + mi * 16 + kg * 4 + j;
                int d = ni * 16 + r16;
                out[((size_t)b * S_ + q) * E_ + h * HD_ + d] = (bf16_t)acc2[mi][ni][j];
            }
}

// ---------------- pooling + concat (wuser folded in) -> outvec[B,768] fp32 ----------------
__global__ __launch_bounds__(256) void pool_kernel(
        const bf16_t* __restrict__ xb, const float* __restrict__ attr_tf,
        const int* __restrict__ lens, const int* __restrict__ lens_user,
        const float* __restrict__ feat, const float* __restrict__ fwW,
        const float* __restrict__ fwb,
        const int* __restrict__ uid, const int* __restrict__ iid,
        const float* __restrict__ user_emb, const float* __restrict__ item_emb,
        float* __restrict__ outvec) {
    int b = blockIdx.x, t = threadIdx.x;
    __shared__ float wrow[S_];
    float z = fwb[0];
    #pragma unroll
    for (int i = 0; i < 13; i++) z += feat[b * 13 + i] * fwW[i];
    float wub = 1.f / (1.f + __expf(-z));
    if (t < S_) {
        float w = (t < lens[b]) ? attr_tf[b * S_ + t] : 0.f;
        float side = (t < lens_user[b]) ? wub : (1.f - wub);
        wrow[t] = w * side;
    }
    __syncthreads();
    float acc = 0.f;
    const bf16_t* xr = xb + (size_t)b * S_ * E_ + t;
    #pragma unroll 4
    for (int s = 0; s < S_; s++) acc += wrow[s] * (float)xr[(size_t)s * E_];
    outvec[b * 768 + 256 + t] = acc;
    outvec[b * 768 + t] = user_emb[(size_t)uid[b] * E_ + t];
    outvec[b * 768 + 512 + t] = item_emb[(size_t)iid[b] * E_ + t];
}

// ---------------- logits + mask + new_targets -> d_out (fp32); 2 targets per wave ----
__global__ __launch_bounds__(256) void logits_kernel(
        const float* __restrict__ outvec, const float* __restrict__ out_emb,
        const int* __restrict__ pos_t, const int* __restrict__ pos_l,
        const int* __restrict__ neg_t, const int* __restrict__ neg_l,
        float* __restrict__ dout) {
    int gg = blockIdx.x * 4 + (threadIdx.x >> 6);
    int lane = threadIdx.x & 63;
    int b = gg / (TT_ / 2);
    int u = gg - b * (TT_ / 2);
    int pl = pos_l[b], nl = neg_l[b];
    int t0 = u * 2, t1 = u * 2 + 1;

    int tgt0, tgt1, valid0, valid1, ispos0, ispos1;
    if (t0 < TPOS_) { tgt0 = pos_t[b * TPOS_ + t0]; valid0 = (t0 < pl); ispos0 = 1; }
    else { int tn = t0 - TPOS_; tgt0 = neg_t[b * TNEG_ + tn]; valid0 = (tn < nl); ispos0 = 0; }
    if (t1 < TPOS_) { tgt1 = pos_t[b * TPOS_ + t1]; valid1 = (t1 < pl); ispos1 = 1; }
    else { int tn = t1 - TPOS_; tgt1 = neg_t[b * TNEG_ + tn]; valid1 = (tn < nl); ispos1 = 0; }

    const float4* e0 = reinterpret_cast<const float4*>(out_emb + (size_t)tgt0 * 768);
    const float4* e1 = reinterpret_cast<const float4*>(out_emb + (size_t)tgt1 * 768);
    const float4* o4 = reinterpret_cast<const float4*>(outvec + (size_t)b * 768);
    float acc0 = 0.f, acc1 = 0.f;
    #pragma unroll
    for (int c = 0; c < 3; c++) {
        float4 a0 = e0[c * 64 + lane];
        float4 a1 = e1[c * 64 + lane];
        float4 o = o4[c * 64 + lane];
        acc0 += a0.x * o.x + a0.y * o.y + a0.z * o.z + a0.w * o.w;
        acc1 += a1.x * o.x + a1.y * o.y + a1.z * o.z + a1.w * o.w;
    }
    #pragma unroll
    for (int m = 1; m < 64; m <<= 1) { acc0 += __shfl_xor(acc0, m); acc1 += __shfl_xor(acc1, m); }
    if (lane == 0) {
        size_t i0 = (size_t)b * TT_ + t0;
        dout[i0] = acc0;
        dout[i0 + 1] = acc1;
        dout[(size_t)B_ * TT_ + i0] = valid0 ? 1.0f : 0.0f;
        dout[(size_t)B_ * TT_ + i0 + 1] = valid1 ? 1.0f : 0.0f;
        dout[2 * (size_t)B_ * TT_ + i0] = (valid0 && ispos0) ? 1.0f : 0.0f;
        dout[2 * (size_t)B_ * TT_ + i0 + 1] = (valid1 && ispos1) ? 1.0f : 0.0f;
    }
}

extern "C" void kernel_launch(void* const* d_in, const int* in_sizes, int n_in,
                              void* d_out, int out_size, void* d_ws, size_t ws_size,
                              hipStream_t stream) {
    const int*   attr        = (const int*)d_in[0];
    const float* attr_tf     = (const float*)d_in[2];
    const float* attr_feat   = (const float*)d_in[3];
    const int*   attr_lens   = (const int*)d_in[4];
    const int*   attr_lens_u = (const int*)d_in[5];
    const int*   user_ids    = (const int*)d_in[7];
    const int*   item_ids    = (const int*)d_in[8];
    const int*   pos_targets = (const int*)d_in[9];
    const int*   pos_lens    = (const int*)d_in[10];
    const int*   neg_targets = (const int*)d_in[11];
    const int*   neg_lens    = (const int*)d_in[12];
    const float* attr_emb    = (const float*)d_in[13];
    const float* user_emb    = (const float*)d_in[14];
    const float* item_emb    = (const float*)d_in[15];
    const float* out_emb     = (const float*)d_in[16];
    const float* fw_W        = (const float*)d_in[17];
    const float* fw_b        = (const float*)d_in[18];
    const float* qkv_w       = (const float*)d_in[19];
    const float* qkv_b       = (const float*)d_in[20];
    const float* attn_out_w  = (const float*)d_in[21];
    const float* attn_out_b  = (const float*)d_in[22];
    const float* ln1_s       = (const float*)d_in[23];
    const float* ln1_b       = (const float*)d_in[24];
    const float* ff1_w       = (const float*)d_in[25];
    const float* ff1_b       = (const float*)d_in[26];
    const float* ff2_w       = (const float*)d_in[27];
    const float* ff2_b       = (const float*)d_in[28];
    const float* ln2_s       = (const float*)d_in[29];
    const float* ln2_b       = (const float*)d_in[30];

    // ---- workspace plan ----
    size_t szRes = (size_t)ROWS_ * E_ * 2;
    size_t wB = (size_t)1572864 * 2;
    size_t fixedB = 2 * szRes + wB + (size_t)B_ * 768 * 4 + 4096 + 16384;
    int CH = 32;
    for (int ch = 1; ch <= 32; ch <<= 1) {
        if (fixedB + (size_t)(ROWS_ / ch) * 1024 * 2 <= ws_size) { CH = ch; break; }
    }
    int rowsC = ROWS_ / CH, sampC = B_ / CH;

    char* ws = (char*)d_ws;
    size_t off = 0;
    auto alloc = [&](size_t bytes) { void* pp = ws + off; off += (bytes + 255) & ~255ULL; return pp; };
    bf16_t* xb  = (bf16_t*)alloc(szRes);
    bf16_t* ob  = (bf16_t*)alloc(szRes);
    bf16_t* wq  = (bf16_t*)alloc((size_t)393216 * 2);
    bf16_t* wa  = (bf16_t*)alloc((size_t)131072 * 2);
    bf16_t* w1  = (bf16_t*)alloc((size_t)524288 * 2);
    bf16_t* w2  = (bf16_t*)alloc((size_t)524288 * 2);
    float* outvec = (float*)alloc((size_t)B_ * 768 * 4);
    bf16_t* chunk = (bf16_t*)alloc((size_t)rowsC * 1024 * 2);

    cvtall_kernel<<<768, 256, 0, stream>>>(qkv_w, attn_out_w, ff1_w, ff2_w, wq, wa, w1, w2);
    embed_kernel<<<ROWS_ / 4, 256, 0, stream>>>(attr, attr_emb, xb);

    for (int l = 0; l < 2; l++) {
        for (int c = 0; c < CH; c++) {
            size_t r0 = (size_t)c * rowsC;
            gemm8_kernel<false><<<dim3(3, rowsC / 128), 512, 0, stream>>>(
                xb + r0 * E_, wq + (size_t)l * 768 * 256, qkv_b + l * 768, chunk, rowsC, 768, 256);
            attn_kernel<<<sampC * H_, 256, 0, stream>>>(chunk, attr_lens + c * sampC, ob + r0 * E_);
        }
        gemm_ln8_kernel<<<ROWS_ / 128, 512, 0, stream>>>(
            ob, wa + (size_t)l * 256 * 256, attn_out_b + l * 256,
            ln1_s + l * 256, ln1_b + l * 256, xb, ROWS_, 256);
        for (int c = 0; c < CH; c++) {
            size_t r0 = (size_t)c * rowsC;
            gemm8_kernel<true><<<dim3(4, rowsC / 128), 512, 0, stream>>>(
                xb + r0 * E_, w1 + (size_t)l * 1024 * 256, ff1_b + l * 1024, chunk, rowsC, 1024, 256);
            gemm_ln8_kernel<<<rowsC / 128, 512, 0, stream>>>(
                chunk, w2 + (size_t)l * 256 * 1024, ff2_b + l * 256,
                ln2_s + l * 256, ln2_b + l * 256, xb + r0 * E_, rowsC, 1024);
        }
    }

    pool_kernel<<<B_, 256, 0, stream>>>(xb, attr_tf, attr_lens, attr_lens_u,
                                        attr_feat, fw_W, fw_b,
                                        user_ids, item_ids, user_emb, item_emb, outvec);
    logits_kernel<<<B_ * TT_ / 8, 256, 0, stream>>>(outvec, out_emb, pos_targets, pos_lens,
                                                    neg_targets, neg_lens, (float*)d_out);
}